// Round 12
// baseline (772.840 us; speedup 1.0000x reference)
//
#include <hip/hip_runtime.h>
#include <math.h>

#define D_MODEL 768
#define D_STATE 16
#define D_CONV  4
#define D_INNER 1536
#define BATCH   2
#define SEQ     512
#define M_ROWS  (BATCH * SEQ)            // 1024
#define N_XZ    (2 * D_INNER)            // 3072
#define N_XDBL  (D_INNER + 2 * D_STATE)  // 1568

typedef _Float16 half8 __attribute__((ext_vector_type(8)));
typedef float  f32x4  __attribute__((ext_vector_type(4)));
typedef unsigned short ushort_t;
typedef ushort_t ushort8_t __attribute__((ext_vector_type(8)));

__device__ __forceinline__ ushort_t f2h(float f) {
    _Float16 h = (_Float16)f;
    return *(ushort_t*)&h;
}
__device__ __forceinline__ float h2f(ushort_t u) {
    return (float)(*(const _Float16*)&u);
}
__device__ __forceinline__ void pack8(const float* s, ushort_t* d) {
    ushort8_t o;
#pragma unroll
    for (int j = 0; j < 8; ++j) o[j] = f2h(s[j]);
    *(ushort8_t*)d = o;
}
__device__ __forceinline__ void gld16(const ushort_t* g, void* l) {
    __builtin_amdgcn_global_load_lds((const __attribute__((address_space(1))) void*)g,
                                     (__attribute__((address_space(3))) void*)l, 16, 0, 0);
}

#define SX   (M_ROWS * D_MODEL)
#define SW1  (N_XZ * D_MODEL)
#define SW2  (N_XDBL * D_INNER)
#define SWDT (D_INNER * D_INNER)
#define SWO  (D_MODEL * D_INNER)
#define SPACK (SX + SW1 + SW2 + SWDT + SWO)

#define PSG1 ((long)M_ROWS * N_XZ)
#define PSG3 ((long)M_ROWS * N_XDBL)
#define PSG4 ((long)D_INNER * M_ROWS)
#define PSG6 ((long)M_ROWS * D_MODEL)

#define NBLK 384

struct Params {
    const float *x, *W_in, *conv_w, *conv_b, *W_x, *W_dt, *b_dt, *A_log, *Dp, *W_out;
    float* out;
    ushort_t *xs, *w1, *w2, *wdt16, *wo16, *xc, *xd, *u_i, *uT, *P16;
    float *Pf, *xconvT, *zsiluT, *BCT;
    unsigned* bar;                       // [0]=counter, [1]=generation
};

// ---------------------------------------------------------------------------
// Software grid barrier (generation counter, agent scope). All NBLK blocks
// are co-resident by construction (384 blocks <= 2/CU * 256 CU capacity at
// 48 KB LDS, launch_bounds(512,4) -> VGPR<=128; 25% margin). threadfence on
// both sides gives cross-XCD L2 writeback/invalidate (release/acquire).
// Bounded spin = anti-hang valve only (never triggers when resident).
// ---------------------------------------------------------------------------
__device__ __forceinline__ void grid_barrier(unsigned* bar) {
    __syncthreads();
    if (threadIdx.x == 0) {
        __threadfence();
        unsigned gen = __hip_atomic_load(bar + 1, __ATOMIC_RELAXED, __HIP_MEMORY_SCOPE_AGENT);
        unsigned prev = __hip_atomic_fetch_add(bar, 1u, __ATOMIC_ACQ_REL, __HIP_MEMORY_SCOPE_AGENT);
        if (prev == (unsigned)(NBLK - 1)) {
            __hip_atomic_store(bar, 0u, __ATOMIC_RELAXED, __HIP_MEMORY_SCOPE_AGENT);
            __hip_atomic_fetch_add(bar + 1, 1u, __ATOMIC_RELEASE, __HIP_MEMORY_SCOPE_AGENT);
        } else {
            long spins = 0;
            while (__hip_atomic_load(bar + 1, __ATOMIC_RELAXED, __HIP_MEMORY_SCOPE_AGENT) == gen) {
                __builtin_amdgcn_s_sleep(2);
                if (++spins > (1L << 26)) break;
            }
        }
        __threadfence();
    }
    __syncthreads();
}

// ---------------------------------------------------------------------------
// One GEMM tile — R7/R8 proven body: 128x128, 8 waves, 3-buffer LDS,
// depth-1 counted-vmcnt schedule. Caller must __syncthreads() between tiles.
// ---------------------------------------------------------------------------
template<int HALF_OUT>
__device__ __forceinline__ void gemm_tile(
    ushort_t* smA, ushort_t* smB,
    const ushort_t* __restrict__ A, int lda,
    const ushort_t* __restrict__ B, int ldb,
    void* Cbase, long pstride, int ldc, int N, int kc,
    int bx, int by, int z, int tid)
{
    const int w    = tid >> 6;
    const int lane = tid & 63;
    const int lr   = lane & 15;
    const int lq   = lane >> 4;

    ushort_t* Ch = (ushort_t*)Cbase + (long)z * pstride;
    float*    Cf = (float*)Cbase + (long)z * pstride;

    const int bm = by * 128;
    const int bn = bx * 128;
    const int k0base = z * kc;

    auto stage = [&](int buf, int k0) {
        {
            const int rA = bm + w * 16 + lr;
            gld16(A + (long)rA * lda + k0 + lq * 8, smA + buf * 4096 + w * 512);
        }
        {
            int rB = bn + w * 16 + lr; if (rB >= N) rB = N - 1;
            gld16(B + (long)rB * ldb + k0 + lq * 8, smB + buf * 4096 + w * 512);
        }
    };

    f32x4 acc[4][2] = {};
    const int wm = (w & 1) * 64;
    const int wn = (w >> 1) * 32;

    const int nIter = kc >> 5;
    stage(0, k0base);
    int cur = 0;
    for (int it = 0; it < nIter; ++it) {
        const int nxt = (cur == 2) ? 0 : cur + 1;
        if (it + 1 < nIter) {
            stage(nxt, k0base + (it + 1) * 32);
            asm volatile("s_waitcnt vmcnt(2)" ::: "memory");
        } else {
            asm volatile("s_waitcnt vmcnt(0)" ::: "memory");
        }
        __builtin_amdgcn_s_barrier();
        asm volatile("" ::: "memory");

        half8 ah[4], bh[2];
#pragma unroll
        for (int mt = 0; mt < 4; ++mt)
            ah[mt] = *(const half8*)&smA[cur * 4096 + (((w & 1) * 4 + mt) * 512) + lq * 128 + lr * 8];
#pragma unroll
        for (int nt = 0; nt < 2; ++nt)
            bh[nt] = *(const half8*)&smB[cur * 4096 + (((w >> 1) * 2 + nt) * 512) + lq * 128 + lr * 8];
#pragma unroll
        for (int mt = 0; mt < 4; ++mt)
#pragma unroll
            for (int nt = 0; nt < 2; ++nt)
                acc[mt][nt] = __builtin_amdgcn_mfma_f32_16x16x32_f16(ah[mt], bh[nt], acc[mt][nt], 0, 0, 0);
        cur = nxt;
    }

    // C/D layout: col = lane&15, row = (lane>>4)*4 + reg  [m89/m91]
#pragma unroll
    for (int mt = 0; mt < 4; ++mt)
#pragma unroll
        for (int nt = 0; nt < 2; ++nt)
#pragma unroll
            for (int r = 0; r < 4; ++r) {
                int row = bm + wm + mt * 16 + lq * 4 + r;
                int col = bn + wn + nt * 16 + lr;
                if (col >= N) continue;
                if (HALF_OUT) Ch[(long)row * ldc + col] = f2h(acc[mt][nt][r]);
                else          Cf[(long)row * ldc + col] = acc[mt][nt][r];
            }
}

// ---------------------------------------------------------------------------
// Megakernel: all 10 phases, 9 software grid barriers.
// 384 blocks x 512 threads, persistent, grid-stride over phase tiles.
// ---------------------------------------------------------------------------
__global__ __launch_bounds__(512, 4) void mega_kernel(Params p)
{
    __shared__ __align__(16) unsigned char smem[49152];
    ushort_t* smA = (ushort_t*)smem;                 // 3*4096 ushort = 24 KB
    ushort_t* smB = (ushort_t*)(smem + 24576);       // 24 KB

    const int tid = threadIdx.x;
    const int bid = blockIdx.x;
    const int NB  = NBLK;

    // ---- P0: pack all fp32 operands -> fp16 ----
    for (long v = (long)bid * 512 + tid; v < SPACK / 8; v += (long)NB * 512) {
        long i = v * 8;
        const float* src; ushort_t* dst; long base;
        if (i < SX)                         { src = p.x;    dst = p.xs;    base = i; }
        else if (i < SX + SW1)              { src = p.W_in; dst = p.w1;    base = i - SX; }
        else if (i < SX + SW1 + SW2)        { src = p.W_x;  dst = p.w2;    base = i - SX - SW1; }
        else if (i < SX + SW1 + SW2 + SWDT) { src = p.W_dt; dst = p.wdt16; base = i - SX - SW1 - SW2; }
        else                                { src = p.W_out;dst = p.wo16;  base = i - SX - SW1 - SW2 - SWDT; }
        float vv[8];
        *(float4*)(vv)     = *(const float4*)(src + base);
        *(float4*)(vv + 4) = *(const float4*)(src + base + 4);
        pack8(vv, dst + base);
    }
    grid_barrier(p.bar);

    // ---- P1: G1  xz = x @ W_in^T  (M=1024,N=3072,K=768), z=4, kc=192, fp16 ----
    for (int t = bid; t < 768; t += NB) {
        gemm_tile<1>(smA, smB, p.xs, D_MODEL, p.w1, D_MODEL,
                     p.P16, PSG1, N_XZ, N_XZ, D_MODEL / 4,
                     t % 24, (t / 24) % 8, t / 192, tid);
        __syncthreads();
    }
    grid_barrier(p.bar);

    // ---- P2: conv + SiLU + z-gate (merge 4 fp16 partials) ----
    {
        float* Tx = (float*)smem;                    // [64][33]
        float* Tz = Tx + 64 * 33;
        const ushort_t* P = p.P16;
        for (int tu = bid; tu < 768; tu += NB) {
            const int rb = tu & 31;                  // 32 r-tiles of 32 rows
            const int db = tu >> 5;                  // 24 d-tiles
            const int dl = tid & 63;
            const int d  = db * 64 + dl;
            const int rr = tid >> 6;                 // 0..7
            const float w0 = p.conv_w[d * 4 + 0], w1v = p.conv_w[d * 4 + 1];
            const float w2v = p.conv_w[d * 4 + 2], w3v = p.conv_w[d * 4 + 3];
            const float bb = p.conv_b[d];
            auto mrg = [&](long o) {
                return h2f(P[o]) + h2f(P[o + PSG1]) + h2f(P[o + 2 * PSG1]) + h2f(P[o + 3 * PSG1]);
            };
            __syncthreads();                         // LDS reuse across tiles
#pragma unroll
            for (int q = 0; q < 4; ++q) {
                const int r = rb * 32 + q * 8 + rr;
                const int l = r & (SEQ - 1);
                float acc = bb;
                if (l >= 3) acc = fmaf(w0,  mrg((long)(r - 3) * N_XZ + d), acc);
                if (l >= 2) acc = fmaf(w1v, mrg((long)(r - 2) * N_XZ + d), acc);
                if (l >= 1) acc = fmaf(w2v, mrg((long)(r - 1) * N_XZ + d), acc);
                acc = fmaf(w3v, mrg((long)r * N_XZ + d), acc);
                float s = acc / (1.f + expf(-acc));
                p.xc[(long)r * D_INNER + d] = f2h(s);
                float zv = mrg((long)r * N_XZ + D_INNER + d);
                Tx[dl * 33 + q * 8 + rr] = s;
                Tz[dl * 33 + q * 8 + rr] = zv / (1.f + expf(-zv));
            }
            __syncthreads();
            const int rp = tid & 31;
            const int dp = (tid >> 5) & 15;
#pragma unroll
            for (int pp = 0; pp < 4; ++pp) {
                int dd = pp * 16 + dp;
                long o = (long)(db * 64 + dd) * M_ROWS + rb * 32 + rp;
                p.xconvT[o] = Tx[dd * 33 + rp];
                p.zsiluT[o] = Tz[dd * 33 + rp];
            }
        }
    }
    grid_barrier(p.bar);

    // ---- P3: G3  x_dbl = xconv @ W_x^T  (M=1024,N=1568,K=1536), z=3, fp32 ----
    for (int t = bid; t < 312; t += NB) {
        gemm_tile<0>(smA, smB, p.xc, D_INNER, p.w2, D_INNER,
                     p.Pf, PSG3, N_XDBL, N_XDBL, D_INNER / 3,
                     t % 13, (t / 13) % 8, t / 104, tid);
        __syncthreads();
    }
    grid_barrier(p.bar);

    // ---- P4: ep_xdbl (merge 3 fp32 partials -> xd fp16 + BCT) ----
    for (long v = (long)bid * 512 + tid; v < (long)M_ROWS * N_XDBL / 8; v += (long)NB * 512) {
        long i = v * 8;
        int row = (int)(i / N_XDBL);
        int col = (int)(i - (long)row * N_XDBL);
        float f[8];
#pragma unroll
        for (int j = 0; j < 8; ++j)
            f[j] = p.Pf[i + j] + p.Pf[i + j + PSG3] + p.Pf[i + j + 2 * PSG3];
        pack8(f, p.xd + i);
        if (col >= D_INNER) {
#pragma unroll
            for (int j = 0; j < 8; ++j)
                p.BCT[(long)(col + j - D_INNER) * M_ROWS + row] = f[j];
        }
    }
    grid_barrier(p.bar);

    // ---- P5: G4  delta_pre = W_dt @ x_dbl^T  (M=1536,N=1024,K=1536), z=8, fp16 ----
    for (int t = bid; t < 768; t += NB) {
        gemm_tile<1>(smA, smB, p.wdt16, D_INNER, p.xd, N_XDBL,
                     p.P16, PSG4, M_ROWS, M_ROWS, D_INNER / 8,
                     t % 8, (t / 8) % 12, t / 96, tid);
        __syncthreads();
    }
    grid_barrier(p.bar);

    // ---- P6: scan (merge 8 fp16 partials, softplus, KS lane scan) ----
    {
        float* S = (float*)smem;                     // 2 halves x 2560 floats
        const int w    = tid >> 6;
        const int half = w >> 2;                     // 0..1
        const int wl   = w & 3;
        const int t64  = tid & 63;
        float* dlT = S + half * 2560;
        float* xrT = dlT + 512;
        float* red = xrT + 512;                      // 3*512
        for (int u = bid; u < 1536; u += NB) {
            const int bd = 2 * u + half;
            const int b  = bd / D_INNER;
            const int d  = bd % D_INNER;
            const long od = (long)d * M_ROWS + b * SEQ;
            const float bdt = p.b_dt[d];
            __syncthreads();                         // LDS reuse across units
            const int lh = tid & 255;
#pragma unroll
            for (int q = 0; q < 2; ++q) {
                const int l = lh + q * 256;
                float v = bdt;
#pragma unroll
                for (int z = 0; z < 8; ++z) v += h2f(p.P16[od + l + z * PSG4]);
                float sp = fmaxf(v, 0.f) + log1pf(expf(-fabsf(v)));
                const int li = (l & 7) * 64 + (l >> 3);
                dlT[li] = sp;
                xrT[li] = p.xconvT[od + l];
            }
            __syncthreads();

            float dl[8], xr[8], dx[8], yac[8];
#pragma unroll
            for (int j = 0; j < 8; ++j) {
                dl[j] = dlT[j * 64 + t64];
                xr[j] = xrT[j * 64 + t64];
                dx[j] = dl[j] * xr[j];
                yac[j] = 0.f;
            }
            const int l0 = 8 * t64;
#pragma unroll
            for (int nn = 0; nn < 4; ++nn) {
                const int n = wl * 4 + nn;
                const float Adn = -expf(p.A_log[d * D_STATE + n]);
                const float4* Bp = (const float4*)(p.BCT + (long)n * M_ROWS + b * SEQ + l0);
                float4 b0 = Bp[0], b1 = Bp[1];
                float Bv[8] = {b0.x, b0.y, b0.z, b0.w, b1.x, b1.y, b1.z, b1.w};
                float c[8], v[8];
#pragma unroll
                for (int j = 0; j < 8; ++j) {
                    c[j] = __expf(dl[j] * Adn);
                    v[j] = fabsf(dx[j] * Bv[j]);
                }
                float c01 = c[1] * c[0], v01 = fmaf(c[1], v[0], v[1]);
                float c23 = c[3] * c[2], v23 = fmaf(c[3], v[2], v[3]);
                float c45 = c[5] * c[4], v45 = fmaf(c[5], v[4], v[5]);
                float c67 = c[7] * c[6], v67 = fmaf(c[7], v[6], v[7]);
                float c03 = c23 * c01,  v03 = fmaf(c23, v01, v23);
                float c47 = c67 * c45,  v47 = fmaf(c67, v45, v67);
                float cA  = c47 * c03,  vA  = fmaf(c47, v03, v47);
#pragma unroll
                for (int h = 1; h <= 32; h <<= 1) {
                    float cl = __shfl_up(cA, (unsigned)h);
                    float vl = __shfl_up(vA, (unsigned)h);
                    if (t64 >= h) { vA = fmaf(cA, vl, vA); cA = cA * cl; }
                }
                float s = __shfl_up(vA, 1u);
                if (t64 == 0) s = 0.f;
                const float4* Cp = (const float4*)(p.BCT + (long)(16 + n) * M_ROWS + b * SEQ + l0);
                float4 c0 = Cp[0], c1 = Cp[1];
                float Cv[8] = {c0.x, c0.y, c0.z, c0.w, c1.x, c1.y, c1.z, c1.w};
#pragma unroll
                for (int j = 0; j < 8; ++j) {
                    s = fmaf(c[j], s, v[j]);
                    yac[j] = fmaf(s, Cv[j], yac[j]);
                }
            }

            if (wl) {
#pragma unroll
                for (int j = 0; j < 8; ++j) red[(wl - 1) * 512 + j * 64 + t64] = yac[j];
            }
            __syncthreads();
            if (wl == 0) {
                const float Dpd = p.Dp[d];
                ushort8_t uo;
#pragma unroll
                for (int j = 0; j < 8; ++j) {
                    float y = yac[j] + red[j * 64 + t64] + red[512 + j * 64 + t64] + red[1024 + j * 64 + t64];
                    float uv = fmaf(xr[j], Dpd, y) * p.zsiluT[od + l0 + j];
                    uo[j] = f2h(uv);
                }
                *(ushort8_t*)(p.uT + od + l0) = uo;
            }
        }
    }
    grid_barrier(p.bar);

    // ---- P7: transpose uT -> u fp16 ----
    {
        ushort_t* T = (ushort_t*)smem;               // [64][65]
        for (int tu = bid; tu < 384; tu += NB) {
            const int m0 = (tu & 15) * 64;
            const int d0 = (tu >> 4) * 64;
            const int c  = tid & 63;
            const int rr = tid >> 6;                 // 0..7
            __syncthreads();
#pragma unroll
            for (int pp = 0; pp < 64; pp += 8)
                T[(pp + rr) * 65 + c] = p.uT[(long)(d0 + pp + rr) * M_ROWS + m0 + c];
            __syncthreads();
#pragma unroll
            for (int pp = 0; pp < 64; pp += 8) {
                int rm = pp + rr;
                p.u_i[(long)(m0 + rm) * D_INNER + (d0 + c)] = T[c * 65 + rm];
            }
        }
    }
    grid_barrier(p.bar);

    // ---- P8: G6  out = u @ W_out^T  (M=1024,N=768,K=1536), z=16, fp16 ----
    for (int t = bid; t < 768; t += NB) {
        gemm_tile<1>(smA, smB, p.u_i, D_INNER, p.wo16, D_INNER,
                     p.P16, PSG6, D_MODEL, D_MODEL, D_INNER / 16,
                     t % 6, (t / 6) % 8, t / 48, tid);
        __syncthreads();
    }
    grid_barrier(p.bar);

    // ---- P9: merge 16 fp16 partials -> out fp32 ----
    for (long v = (long)bid * 512 + tid; v < (long)M_ROWS * D_MODEL / 8; v += (long)NB * 512) {
        long i = v * 8;
        float o[8] = {};
#pragma unroll
        for (int z = 0; z < 16; ++z) {
            ushort8_t vv = *(const ushort8_t*)(p.P16 + i + z * PSG6);
#pragma unroll
            for (int j = 0; j < 8; ++j) o[j] += h2f(vv[j]);
        }
        *(float4*)(p.out + i)     = *(float4*)(o);
        *(float4*)(p.out + i + 4) = *(float4*)(o + 4);
    }
}

// ---------------------------------------------------------------------------
extern "C" void kernel_launch(void* const* d_in, const int* in_sizes, int n_in,
                              void* d_out, int out_size, void* d_ws, size_t ws_size,
                              hipStream_t stream)
{
    (void)in_sizes; (void)n_in; (void)out_size; (void)ws_size;

    Params p;
    p.x      = (const float*)d_in[0];
    p.W_in   = (const float*)d_in[1];
    p.conv_w = (const float*)d_in[2];
    p.conv_b = (const float*)d_in[3];
    p.W_x    = (const float*)d_in[4];
    p.W_dt   = (const float*)d_in[5];
    p.b_dt   = (const float*)d_in[6];
    p.A_log  = (const float*)d_in[7];
    p.Dp     = (const float*)d_in[8];
    p.W_out  = (const float*)d_in[9];
    p.out    = (float*)d_out;

    // workspace layout (R8's proven aliasing):
    // P: G1 fp16 z4 -> G3 fp32 z3 -> G4 fp16 z8 -> G6 fp16 z16 (all fit).
    float* ws = (float*)d_ws;
    long off = 0;
    float* P      = ws + off; off += 2L * M_ROWS * N_XZ;          // 6,291,456 fl
    float* xconvT = ws + off; off += (long)D_INNER * M_ROWS;
    float* zsiluT = ws + off; off += (long)D_INNER * M_ROWS;
    float* uTbuf  = ws + off; off += (long)D_INNER * M_ROWS / 2;  // fp16
    float* xsbuf  = ws + off; off += (long)M_ROWS * D_MODEL / 2;  // fp16
    float* w1buf  = ws + off; off += (long)N_XZ * D_MODEL / 2;    // fp16
    float* w2buf  = ws + off; off += (long)N_XDBL * D_INNER / 2;  // fp16
    float* wdtbuf = ws + off; off += (long)D_INNER * D_INNER / 2; // fp16
    float* wobuf  = ws + off; off += (long)D_MODEL * D_INNER / 2; // fp16
    float* xcbuf  = ws + off; off += (long)M_ROWS * D_INNER / 2;  // fp16
    float* xdbuf  = ws + off; off += (long)M_ROWS * N_XDBL / 2;   // fp16
    float* BCT    = ws + off; off += (long)2 * D_STATE * M_ROWS;
    off = (off + 63) & ~63L;
    unsigned* bar = (unsigned*)(ws + off);           // barrier state (64 B)

    p.xs    = (ushort_t*)xsbuf;
    p.w1    = (ushort_t*)w1buf;
    p.w2    = (ushort_t*)w2buf;
    p.wdt16 = (ushort_t*)wdtbuf;
    p.wo16  = (ushort_t*)wobuf;
    p.xc    = (ushort_t*)xcbuf;          // conv fp16 out (G3 A)
    p.xd    = (ushort_t*)xdbuf;          // x_dbl fp16 (G4 B)
    p.u_i   = (ushort_t*)xcbuf;          // u fp16 (G6 A; xc dead after P3)
    p.uT    = (ushort_t*)uTbuf;
    p.P16   = (ushort_t*)P;
    p.Pf    = P;
    p.xconvT = xconvT;
    p.zsiluT = zsiluT;
    p.BCT    = BCT;
    p.bar    = bar;

    hipMemsetAsync(bar, 0, 64, stream);
    mega_kernel<<<dim3(NBLK), dim3(512), 0, stream>>>(p);
}

// Round 13
// 205.298 us; speedup vs baseline: 3.7645x; 3.7645x over previous
//
#include <hip/hip_runtime.h>
#include <math.h>

#define D_MODEL 768
#define D_STATE 16
#define D_CONV  4
#define D_INNER 1536
#define BATCH   2
#define SEQ     512
#define M_ROWS  (BATCH * SEQ)            // 1024
#define N_XZ    (2 * D_INNER)            // 3072
#define N_XDBL  (D_INNER + 2 * D_STATE)  // 1568

typedef _Float16 half8 __attribute__((ext_vector_type(8)));
typedef float  f32x4  __attribute__((ext_vector_type(4)));
typedef unsigned short ushort_t;
typedef ushort_t ushort8_t __attribute__((ext_vector_type(8)));

// ---- fp16 helpers (RNE via HW cvt), raw ushort storage ----
__device__ __forceinline__ ushort_t f2h(float f) {
    _Float16 h = (_Float16)f;
    return *(ushort_t*)&h;
}
__device__ __forceinline__ float h2f(ushort_t u) {
    return (float)(*(const _Float16*)&u);
}
__device__ __forceinline__ void pack8(const float* s, ushort_t* d) {
    ushort8_t o;
#pragma unroll
    for (int j = 0; j < 8; ++j) o[j] = f2h(s[j]);
    *(ushort8_t*)d = o;
}
// async global(16B/lane) -> LDS (wave-uniform base + lane*16)  [m03/m97/m104]
__device__ __forceinline__ void gld16(const ushort_t* g, void* l) {
    __builtin_amdgcn_global_load_lds((const __attribute__((address_space(1))) void*)g,
                                     (__attribute__((address_space(3))) void*)l, 16, 0, 0);
}

// ---------------------------------------------------------------------------
// Pack kernel: all five fp32->fp16 conversions + zeroes `out` (G6 is
// split-K-atomic now, so out must start at 0 — done here at pipeline start,
// no extra dispatch, no reliance on harness poison semantics).
// ---------------------------------------------------------------------------
#define SX   (M_ROWS * D_MODEL)
#define SW1  (N_XZ * D_MODEL)
#define SW2  (N_XDBL * D_INNER)
#define SWDT (D_INNER * D_INNER)
#define SWO  (D_MODEL * D_INNER)
#define SPACK (SX + SW1 + SW2 + SWDT + SWO)    // 9,093,120 (multiple of 2048)
#define SOUT  (M_ROWS * D_MODEL)               // 786,432 (multiple of 2048)
__global__ __launch_bounds__(256) void pack_kernel(
    const float* __restrict__ x, const float* __restrict__ win,
    const float* __restrict__ wx, const float* __restrict__ wdt,
    const float* __restrict__ wo,
    ushort_t* __restrict__ xs, ushort_t* __restrict__ w1, ushort_t* __restrict__ w2,
    ushort_t* __restrict__ wdt16, ushort_t* __restrict__ wo16,
    float* __restrict__ out)
{
    long i = ((long)blockIdx.x * 256 + threadIdx.x) * 8;
    if (i >= SPACK) {                           // tail region: zero `out`
        long o = i - SPACK;
        if (o < SOUT) {
            float4 z = make_float4(0.f, 0.f, 0.f, 0.f);
            *(float4*)(out + o)     = z;
            *(float4*)(out + o + 4) = z;
        }
        return;
    }
    const float* src; ushort_t* dst; long base;
    if (i < SX)                         { src = x;   dst = xs;    base = i; }
    else if (i < SX + SW1)              { src = win; dst = w1;    base = i - SX; }
    else if (i < SX + SW1 + SW2)        { src = wx;  dst = w2;    base = i - SX - SW1; }
    else if (i < SX + SW1 + SW2 + SWDT) { src = wdt; dst = wdt16; base = i - SX - SW1 - SW2; }
    else                                { src = wo;  dst = wo16;  base = i - SX - SW1 - SW2 - SWDT; }
    float v[8];
    *(float4*)(v)     = *(const float4*)(src + base);
    *(float4*)(v + 4) = *(const float4*)(src + base + 4);
    pack8(v, dst + base);
}

// ---------------------------------------------------------------------------
// fp16 MFMA GEMM — 128x128 tile, 8 waves (512 threads), z-split,
// 3-buffer depth-1 counted-vmcnt schedule (R4/R7 proven, best @203.05).
// MODE 0: fp32 partial store. MODE 1: fp16 partial store.
// MODE 2: split-K ATOMIC — fp32 unsafeAtomicAdd directly into C (out);
//         z selects only the K-range (pstride = 0). Eliminates the merge
//         kernel and the fp16 rounding of G6 partials.
// ---------------------------------------------------------------------------
template<int MODE>
__global__ __launch_bounds__(512) void gemm_lds(
    const ushort_t* __restrict__ A, int lda,   // lda = K in elems
    const ushort_t* __restrict__ B, int ldb,
    void* __restrict__ Cbase, long pstride, int ldc,
    int N, int kc)                              // kc % 32 == 0
{
    __shared__ ushort_t smA[3][4096];          // 128 rows x 32 k fp16 = 8 KB
    __shared__ ushort_t smB[3][4096];          // x3 bufs x2 mats = 48 KB

    const int tid  = threadIdx.x;
    const int w    = tid >> 6;                 // 0..7
    const int lane = tid & 63;
    const int lr   = lane & 15;
    const int lq   = lane >> 4;

    const int Gx = gridDim.x, Gy = gridDim.y;
    const int T = Gx * Gy * gridDim.z;
    const int f = blockIdx.x + Gx * (blockIdx.y + Gy * blockIdx.z);
    const int g = (T & 7) ? f : ((f & 7) * (T >> 3) + (f >> 3));
    const int bx = g % Gx;
    const int by = (g / Gx) % Gy;
    const int z  = g / (Gx * Gy);
    ushort_t* __restrict__ Ch = (ushort_t*)Cbase + (long)z * pstride;
    float*    __restrict__ Cf = (float*)Cbase + (long)z * pstride;

    const int bm = by * 128;
    const int bn = bx * 128;
    const int k0base = z * kc;

    // stage: wave w loads A row-group w and B row-group w (16 rows x 32 k).
    auto stage = [&](int buf, int k0) {
        {
            const int rA = bm + w * 16 + lr;
            gld16(A + (long)rA * lda + k0 + lq * 8, &smA[buf][w * 512]);
        }
        {
            int rB = bn + w * 16 + lr; if (rB >= N) rB = N - 1;
            gld16(B + (long)rB * ldb + k0 + lq * 8, &smB[buf][w * 512]);
        }
    };

    f32x4 acc[4][2] = {};
    const int wm = (w & 1) * 64;               // 2 M-groups
    const int wn = (w >> 1) * 32;              // 4 N-groups

    const int nIter = kc >> 5;
    stage(0, k0base);                          // 2 loads in flight
    int cur = 0;
    for (int it = 0; it < nIter; ++it) {
        const int nxt = (cur == 2) ? 0 : cur + 1;
        if (it + 1 < nIter) {
            stage(nxt, k0base + (it + 1) * 32);            // +2 -> 4 in flight
            asm volatile("s_waitcnt vmcnt(2)" ::: "memory"); // drain stage(it)
        } else {
            asm volatile("s_waitcnt vmcnt(0)" ::: "memory");
        }
        __builtin_amdgcn_s_barrier();
        asm volatile("" ::: "memory");

        half8 ah[4], bh[2];
#pragma unroll
        for (int mt = 0; mt < 4; ++mt)
            ah[mt] = *(const half8*)&smA[cur][(((w & 1) * 4 + mt) * 512) + lq * 128 + lr * 8];
#pragma unroll
        for (int nt = 0; nt < 2; ++nt)
            bh[nt] = *(const half8*)&smB[cur][(((w >> 1) * 2 + nt) * 512) + lq * 128 + lr * 8];
#pragma unroll
        for (int mt = 0; mt < 4; ++mt)
#pragma unroll
            for (int nt = 0; nt < 2; ++nt)
                acc[mt][nt] = __builtin_amdgcn_mfma_f32_16x16x32_f16(ah[mt], bh[nt], acc[mt][nt], 0, 0, 0);
        cur = nxt;
    }

    // C/D layout: col = lane&15, row = (lane>>4)*4 + reg  [m89/m91]
#pragma unroll
    for (int mt = 0; mt < 4; ++mt)
#pragma unroll
        for (int nt = 0; nt < 2; ++nt)
#pragma unroll
            for (int r = 0; r < 4; ++r) {
                int row = bm + wm + mt * 16 + lq * 4 + r;
                int col = bn + wn + nt * 16 + lr;
                if (col >= N) continue;
                if (MODE == 1)      Ch[(long)row * ldc + col] = f2h(acc[mt][nt][r]);
                else if (MODE == 0) Cf[(long)row * ldc + col] = acc[mt][nt][r];
                else                unsafeAtomicAdd(&Cf[(long)row * ldc + col], acc[mt][nt][r]);
            }
}

// ---------------------------------------------------------------------------
// Depthwise causal conv + bias + SiLU + z-gate SiLU, fused with GEMM1
// split-K merge (p0+p1, fp16 partials). Transposed outputs via padded
// LDS -> coalesced writes. Tile: 64 d x 16 r; grid (64, 24).
// ---------------------------------------------------------------------------
__global__ __launch_bounds__(256) void conv_silu_kernel(
    const ushort_t* __restrict__ p0, const ushort_t* __restrict__ p1,
    const float* __restrict__ conv_w, const float* __restrict__ conv_b,
    float* __restrict__ xconvT, float* __restrict__ zsiluT,
    ushort_t* __restrict__ xc)
{
    __shared__ float Tx[64][17];
    __shared__ float Tz[64][17];
    const int rb = blockIdx.x;             // r tile (16 rows)
    const int db = blockIdx.y;             // d tile (64 ch)
    const int dl = threadIdx.x & 63;
    const int d  = db * 64 + dl;
    const int rr = threadIdx.x >> 6;       // 0..3
    const float w0 = conv_w[d * 4 + 0], w1 = conv_w[d * 4 + 1];
    const float w2 = conv_w[d * 4 + 2], w3 = conv_w[d * 4 + 3];
    const float bb = conv_b[d];
#pragma unroll
    for (int q = 0; q < 4; ++q) {
        const int r = rb * 16 + q * 4 + rr;
        const int l = r & (SEQ - 1);
        float acc = bb;
        if (l >= 3) { long o = (long)(r - 3) * N_XZ + d; acc = fmaf(w0, h2f(p0[o]) + h2f(p1[o]), acc); }
        if (l >= 2) { long o = (long)(r - 2) * N_XZ + d; acc = fmaf(w1, h2f(p0[o]) + h2f(p1[o]), acc); }
        if (l >= 1) { long o = (long)(r - 1) * N_XZ + d; acc = fmaf(w2, h2f(p0[o]) + h2f(p1[o]), acc); }
        { long o = (long)r * N_XZ + d; acc = fmaf(w3, h2f(p0[o]) + h2f(p1[o]), acc); }
        float s = acc / (1.f + expf(-acc));
        xc[(long)r * D_INNER + d] = f2h(s);
        long oz = (long)r * N_XZ + D_INNER + d;
        float zv = h2f(p0[oz]) + h2f(p1[oz]);
        Tx[dl][q * 4 + rr] = s;
        Tz[dl][q * 4 + rr] = zv / (1.f + expf(-zv));
    }
    __syncthreads();
    const int rp = threadIdx.x & 15;
    const int dp = threadIdx.x >> 4;       // 0..15
#pragma unroll
    for (int p = 0; p < 4; ++p) {
        int dd = p * 16 + dp;
        long o = (long)(db * 64 + dd) * M_ROWS + rb * 16 + rp;
        xconvT[o] = Tx[dd][rp];
        zsiluT[o] = Tz[dd][rp];
    }
}

// ---------------------------------------------------------------------------
// GEMM3 epilogue: f = sum of 3 fp32 partials (stride ps) -> xd fp16;
// cols >= 1536 also stored transposed fp32 into BCT.
// ---------------------------------------------------------------------------
__global__ __launch_bounds__(256) void ep_xdbl_kernel(
    const float* __restrict__ P, long ps,
    ushort_t* __restrict__ xd, float* __restrict__ BCT)
{
    long i = ((long)blockIdx.x * 256 + threadIdx.x) * 8;
    if (i >= (long)M_ROWS * N_XDBL) return;
    int row = (int)(i / N_XDBL);
    int col = (int)(i - (long)row * N_XDBL);    // multiple of 8
    float f[8];
#pragma unroll
    for (int j = 0; j < 8; ++j) f[j] = P[i + j] + P[i + j + ps] + P[i + j + 2 * ps];
    pack8(f, xd + i);
    if (col >= D_INNER) {
#pragma unroll
        for (int j = 0; j < 8; ++j)
            BCT[(long)(col + j - D_INNER) * M_ROWS + row] = f[j];
    }
}

// ---------------------------------------------------------------------------
// Scan — one block per (b,d), 4 waves x 4 states; fused softplus merge of
// the 4 fp16 GEMM4 partials; Kogge-Stone lane scan; fp16 uT out.
// ---------------------------------------------------------------------------
__global__ __launch_bounds__(256) void scan_kernel(
    const ushort_t* __restrict__ P, long ps,    // GEMM4 fp16 partials x4
    const float* __restrict__ b_dt,
    const float* __restrict__ xconvT,
    const float* __restrict__ zsiluT,
    const float* __restrict__ BCT,              // (32, 1024)
    const float* __restrict__ A_log,
    const float* __restrict__ Dp,
    ushort_t* __restrict__ uT)
{
    __shared__ float dlT[512];
    __shared__ float xrT[512];
    __shared__ float red[3 * 512];

    const int bid = blockIdx.x;
    const int b   = bid / D_INNER;
    const int d   = bid % D_INNER;
    const int tid = threadIdx.x;
    const int w   = tid >> 6;
    const int t   = tid & 63;
    const long od = (long)d * M_ROWS + b * SEQ;

    const float bdt = b_dt[d];
#pragma unroll
    for (int q = 0; q < 2; ++q) {
        const int l = tid + q * 256;
        float v = h2f(P[od + l]) + h2f(P[od + l + ps]) + h2f(P[od + l + 2 * ps])
                + h2f(P[od + l + 3 * ps]) + bdt;
        float sp = fmaxf(v, 0.f) + log1pf(expf(-fabsf(v)));   // softplus (fused)
        const int li = (l & 7) * 64 + (l >> 3);               // transposed
        dlT[li] = sp;
        xrT[li] = xconvT[od + l];
    }
    __syncthreads();

    float dl[8], xr[8], dx[8], yac[8];
#pragma unroll
    for (int j = 0; j < 8; ++j) {
        dl[j] = dlT[j * 64 + t];
        xr[j] = xrT[j * 64 + t];
        dx[j] = dl[j] * xr[j];
        yac[j] = 0.f;
    }
    const int l0 = 8 * t;

#pragma unroll
    for (int nn = 0; nn < 4; ++nn) {
        const int n = w * 4 + nn;
        const float Adn = -expf(A_log[d * D_STATE + n]);
        const float4* Bp = (const float4*)(BCT + (long)n * M_ROWS + b * SEQ + l0);
        float4 b0 = Bp[0], b1 = Bp[1];
        float Bv[8] = {b0.x, b0.y, b0.z, b0.w, b1.x, b1.y, b1.z, b1.w};
        float c[8], v[8];
#pragma unroll
        for (int j = 0; j < 8; ++j) {
            c[j] = __expf(dl[j] * Adn);
            v[j] = fabsf(dx[j] * Bv[j]);
        }
        // compose tree: (cR*cL, cR*vL + vR), 7 composes, depth 3
        float c01 = c[1] * c[0], v01 = fmaf(c[1], v[0], v[1]);
        float c23 = c[3] * c[2], v23 = fmaf(c[3], v[2], v[3]);
        float c45 = c[5] * c[4], v45 = fmaf(c[5], v[4], v[5]);
        float c67 = c[7] * c[6], v67 = fmaf(c[7], v[6], v[7]);
        float c03 = c23 * c01,  v03 = fmaf(c23, v01, v23);
        float c47 = c67 * c45,  v47 = fmaf(c67, v45, v67);
        float cA  = c47 * c03,  vA  = fmaf(c47, v03, v47);
        // Kogge-Stone inclusive scan over 64 lanes (6 stages)
#pragma unroll
        for (int h = 1; h <= 32; h <<= 1) {
            float cl = __shfl_up(cA, (unsigned)h);
            float vl = __shfl_up(vA, (unsigned)h);
            if (t >= h) { vA = fmaf(cA, vl, vA); cA = cA * cl; }
        }
        float s = __shfl_up(vA, 1u);
        if (t == 0) s = 0.f;
        const float4* Cp = (const float4*)(BCT + (long)(16 + n) * M_ROWS + b * SEQ + l0);
        float4 c0 = Cp[0], c1 = Cp[1];
        float Cv[8] = {c0.x, c0.y, c0.z, c0.w, c1.x, c1.y, c1.z, c1.w};
#pragma unroll
        for (int j = 0; j < 8; ++j) {
            s = fmaf(c[j], s, v[j]);
            yac[j] = fmaf(s, Cv[j], yac[j]);
        }
    }

    if (w) {
#pragma unroll
        for (int j = 0; j < 8; ++j) red[(w - 1) * 512 + j * 64 + t] = yac[j];
    }
    __syncthreads();
    if (w == 0) {
        const float Dpd = Dp[d];
        ushort8_t uo;
#pragma unroll
        for (int j = 0; j < 8; ++j) {
            float y = yac[j] + red[j * 64 + t] + red[512 + j * 64 + t] + red[1024 + j * 64 + t];
            float uv = fmaf(xr[j], Dpd, y) * zsiluT[od + l0 + j];
            uo[j] = f2h(uv);
        }
        *(ushort8_t*)(uT + od + l0) = uo;
    }
}

// ---------------------------------------------------------------------------
// Transpose (fp16 pass-through): uT (1536,1024) -> u (1024,1536).
// ---------------------------------------------------------------------------
__global__ __launch_bounds__(256) void transpose_split_kernel(
    const ushort_t* __restrict__ uT, ushort_t* __restrict__ u)
{
    __shared__ ushort_t T[64][65];
    const int m0 = blockIdx.x * 64;
    const int d0 = blockIdx.y * 64;
    const int c  = threadIdx.x & 63;
    const int rr = threadIdx.x >> 6;
#pragma unroll
    for (int p = 0; p < 64; p += 4)
        T[p + rr][c] = uT[(long)(d0 + p + rr) * M_ROWS + m0 + c];
    __syncthreads();
#pragma unroll
    for (int p = 0; p < 64; p += 4) {
        int rm = p + rr;
        u[(long)(m0 + rm) * D_INNER + (d0 + c)] = T[c][rm];
    }
}

// ---------------------------------------------------------------------------
extern "C" void kernel_launch(void* const* d_in, const int* in_sizes, int n_in,
                              void* d_out, int out_size, void* d_ws, size_t ws_size,
                              hipStream_t stream)
{
    (void)in_sizes; (void)n_in; (void)out_size; (void)ws_size;

    const float* x      = (const float*)d_in[0];
    const float* W_in   = (const float*)d_in[1];
    const float* conv_w = (const float*)d_in[2];
    const float* conv_b = (const float*)d_in[3];
    const float* W_x    = (const float*)d_in[4];
    const float* W_dt   = (const float*)d_in[5];
    const float* b_dt   = (const float*)d_in[6];
    const float* A_log  = (const float*)d_in[7];
    const float* Dp     = (const float*)d_in[8];
    const float* W_out  = (const float*)d_in[9];
    float* out = (float*)d_out;

    // workspace ~66 MB (R8 proven aliasing). P generations:
    // G1 fp16 z2 -> G3 fp32 z3 -> G4 fp16 z4 (scan fuses merge).
    // G6 is split-K-atomic into out directly (no partials, no merge).
    float* ws = (float*)d_ws;
    long off = 0;
    float* P      = ws + off; off += 2L * M_ROWS * N_XZ;          // 6,291,456 fl
    float* xconvT = ws + off; off += (long)D_INNER * M_ROWS;
    float* zsiluT = ws + off; off += (long)D_INNER * M_ROWS;
    float* uTbuf  = ws + off; off += (long)D_INNER * M_ROWS / 2;  // fp16
    float* xsbuf  = ws + off; off += (long)M_ROWS * D_MODEL / 2;  // fp16
    float* w1buf  = ws + off; off += (long)N_XZ * D_MODEL / 2;    // fp16
    float* w2buf  = ws + off; off += (long)N_XDBL * D_INNER / 2;  // fp16
    float* wdtbuf = ws + off; off += (long)D_INNER * D_INNER / 2; // fp16
    float* wobuf  = ws + off; off += (long)D_MODEL * D_INNER / 2; // fp16
    float* xcbuf  = ws + off; off += (long)M_ROWS * D_INNER / 2;  // fp16
    float* xdbuf  = ws + off; off += (long)M_ROWS * N_XDBL / 2;   // fp16
    float* BCT    = ws + off; off += (long)2 * D_STATE * M_ROWS;

    ushort_t* xs    = (ushort_t*)xsbuf;
    ushort_t* w1    = (ushort_t*)w1buf;
    ushort_t* w2    = (ushort_t*)w2buf;
    ushort_t* wdt16 = (ushort_t*)wdtbuf;
    ushort_t* wo16  = (ushort_t*)wobuf;
    ushort_t* xc    = (ushort_t*)xcbuf;          // conv fp16 out (G3 A)
    ushort_t* xd    = (ushort_t*)xdbuf;          // x_dbl fp16 (G4 B)
    ushort_t* u_i   = (ushort_t*)xcbuf;          // u fp16 (G6 A; xc dead)
    ushort_t* uT    = (ushort_t*)uTbuf;          // scan out fp16
    ushort_t* P16   = (ushort_t*)P;              // fp16 partial view of P

    const long psG1 = (long)M_ROWS * N_XZ;       // fp16-elem strides
    const long psG4 = (long)D_INNER * M_ROWS;

    dim3 blk(256);
    dim3 gblk(512);

    // 1) pack all fp32 operands -> fp16 + zero `out` (one kernel)
    pack_kernel<<<dim3((SPACK + SOUT) / 2048), blk, 0, stream>>>(
        x, W_in, W_x, W_dt, W_out, xs, w1, w2, wdt16, wo16, out);
    // 2) xz = x @ W_in^T  (M=1024,N=3072,K=768), z=2 -> fp16 partials
    gemm_lds<1><<<dim3(N_XZ / 128, M_ROWS / 128, 2), gblk, 0, stream>>>(
        xs, D_MODEL, w1, D_MODEL, P16, psG1, N_XZ, N_XZ, D_MODEL / 2);
    // 3) conv + silu (fuses fp16 GEMM1 merge; transposed-write LDS)
    conv_silu_kernel<<<dim3(M_ROWS / 16, D_INNER / 64), blk, 0, stream>>>(
        P16, P16 + psG1, conv_w, conv_b, xconvT, zsiluT, xc);
    // 4) x_dbl partials = xconv @ W_x^T  (M=1024,N=1568,K=1536), z=3, fp32
    gemm_lds<0><<<dim3((N_XDBL + 127) / 128, M_ROWS / 128, 3), gblk, 0, stream>>>(
        xc, D_INNER, w2, D_INNER, P, (long)M_ROWS * N_XDBL, N_XDBL, N_XDBL, D_INNER / 3);
    // 5) merge 3 fp32 partials -> xd fp16 + BCT
    ep_xdbl_kernel<<<dim3((M_ROWS * N_XDBL) / 2048), blk, 0, stream>>>(
        P, (long)M_ROWS * N_XDBL, xd, BCT);
    // 6) delta_pre partials = W_dt @ x_dbl^T  (M=1536,N=1024,K=1536), z=4, fp16
    gemm_lds<1><<<dim3(M_ROWS / 128, D_INNER / 128, 4), gblk, 0, stream>>>(
        wdt16, D_INNER, xd, N_XDBL, P16, psG4, M_ROWS, M_ROWS, D_INNER / 4);
    // 7) scan (fused softplus merge of 4 fp16 partials) -> uT fp16
    scan_kernel<<<dim3(BATCH * D_INNER), blk, 0, stream>>>(
        P16, psG4, b_dt, xconvT, zsiluT, BCT, A_log, Dp, uT);
    // 8) transpose uT -> u fp16 (pass-through)
    transpose_split_kernel<<<dim3(M_ROWS / 64, D_INNER / 64), blk, 0, stream>>>(
        uT, u_i);
    // 9) out += u @ W_out^T  (M=1024,N=768,K=1536), z=6, split-K ATOMIC
    //    (fp32 atomics into out; no partials, no merge kernel)
    gemm_lds<2><<<dim3(D_MODEL / 128, M_ROWS / 128, 6), gblk, 0, stream>>>(
        u_i, D_INNER, wo16, D_INNER, out, 0, D_MODEL, D_MODEL, D_INNER / 6);
}

// Round 14
// 201.647 us; speedup vs baseline: 3.8326x; 1.0181x over previous
//
#include <hip/hip_runtime.h>
#include <math.h>

#define D_MODEL 768
#define D_STATE 16
#define D_CONV  4
#define D_INNER 1536
#define BATCH   2
#define SEQ     512
#define M_ROWS  (BATCH * SEQ)            // 1024
#define N_XZ    (2 * D_INNER)            // 3072
#define N_XDBL  (D_INNER + 2 * D_STATE)  // 1568

typedef _Float16 half8 __attribute__((ext_vector_type(8)));
typedef float  f32x4  __attribute__((ext_vector_type(4)));
typedef unsigned short ushort_t;
typedef ushort_t ushort8_t __attribute__((ext_vector_type(8)));

// ---- fp16 helpers (RNE via HW cvt), raw ushort storage ----
__device__ __forceinline__ ushort_t f2h(float f) {
    _Float16 h = (_Float16)f;
    return *(ushort_t*)&h;
}
__device__ __forceinline__ float h2f(ushort_t u) {
    return (float)(*(const _Float16*)&u);
}
__device__ __forceinline__ void pack8(const float* s, ushort_t* d) {
    ushort8_t o;
#pragma unroll
    for (int j = 0; j < 8; ++j) o[j] = f2h(s[j]);
    *(ushort8_t*)d = o;
}
// async global(16B/lane) -> LDS (wave-uniform base + lane*16)  [m03/m97/m104]
__device__ __forceinline__ void gld16(const ushort_t* g, void* l) {
    __builtin_amdgcn_global_load_lds((const __attribute__((address_space(1))) void*)g,
                                     (__attribute__((address_space(3))) void*)l, 16, 0, 0);
}

// ---------------------------------------------------------------------------
// One pack kernel for all five fp32->fp16 conversions (all static at t=0).
// ---------------------------------------------------------------------------
#define SX   (M_ROWS * D_MODEL)
#define SW1  (N_XZ * D_MODEL)
#define SW2  (N_XDBL * D_INNER)
#define SWDT (D_INNER * D_INNER)
#define SWO  (D_MODEL * D_INNER)
#define SPACK (SX + SW1 + SW2 + SWDT + SWO)    // 9,093,120 (multiple of 2048)
__global__ __launch_bounds__(256) void pack_kernel(
    const float* __restrict__ x, const float* __restrict__ win,
    const float* __restrict__ wx, const float* __restrict__ wdt,
    const float* __restrict__ wo,
    ushort_t* __restrict__ xs, ushort_t* __restrict__ w1, ushort_t* __restrict__ w2,
    ushort_t* __restrict__ wdt16, ushort_t* __restrict__ wo16)
{
    long i = ((long)blockIdx.x * 256 + threadIdx.x) * 8;
    if (i >= SPACK) return;
    const float* src; ushort_t* dst; long base;
    if (i < SX)                         { src = x;   dst = xs;    base = i; }
    else if (i < SX + SW1)              { src = win; dst = w1;    base = i - SX; }
    else if (i < SX + SW1 + SW2)        { src = wx;  dst = w2;    base = i - SX - SW1; }
    else if (i < SX + SW1 + SW2 + SWDT) { src = wdt; dst = wdt16; base = i - SX - SW1 - SW2; }
    else                                { src = wo;  dst = wo16;  base = i - SX - SW1 - SW2 - SWDT; }
    float v[8];
    *(float4*)(v)     = *(const float4*)(src + base);
    *(float4*)(v + 4) = *(const float4*)(src + base + 4);
    pack8(v, dst + base);
}

// ---------------------------------------------------------------------------
// fp16 MFMA GEMM — 128x128 tile, 8 waves (512 threads), z-split partials,
// R7's proven depth-1 counted-vmcnt 3-buffer schedule.
// HALF_OUT=1: partials stored fp16 (ushort) — used where downstream error is
// provably negligible (G1 xz: z-path err ~1.5e-6; G4 delta_pre: self-limiting
// through exp, ~2e-6; G6 out partials: ~1e-6). G3 keeps fp32 (feeds B/C).
// ---------------------------------------------------------------------------
template<int HALF_OUT>
__global__ __launch_bounds__(512) void gemm_lds(
    const ushort_t* __restrict__ A, int lda,   // lda = K in elems
    const ushort_t* __restrict__ B, int ldb,
    void* __restrict__ Cbase, long pstride, int ldc,
    int N, int kc)                              // kc % 32 == 0
{
    __shared__ ushort_t smA[3][4096];          // 128 rows x 32 k fp16 = 8 KB
    __shared__ ushort_t smB[3][4096];          // x3 bufs x2 mats = 48 KB

    const int tid  = threadIdx.x;
    const int w    = tid >> 6;                 // 0..7
    const int lane = tid & 63;
    const int lr   = lane & 15;
    const int lq   = lane >> 4;

    const int Gx = gridDim.x, Gy = gridDim.y;
    const int T = Gx * Gy * gridDim.z;
    const int f = blockIdx.x + Gx * (blockIdx.y + Gy * blockIdx.z);
    const int g = (T & 7) ? f : ((f & 7) * (T >> 3) + (f >> 3));
    const int bx = g % Gx;
    const int by = (g / Gx) % Gy;
    const int z  = g / (Gx * Gy);
    ushort_t* __restrict__ Ch = (ushort_t*)Cbase + (long)z * pstride;
    float*    __restrict__ Cf = (float*)Cbase + (long)z * pstride;

    const int bm = by * 128;
    const int bn = bx * 128;
    const int k0base = z * kc;

    // stage: wave w loads A row-group w and B row-group w (16 rows x 32 k).
    auto stage = [&](int buf, int k0) {
        {
            const int rA = bm + w * 16 + lr;
            gld16(A + (long)rA * lda + k0 + lq * 8, &smA[buf][w * 512]);
        }
        {
            int rB = bn + w * 16 + lr; if (rB >= N) rB = N - 1;
            gld16(B + (long)rB * ldb + k0 + lq * 8, &smB[buf][w * 512]);
        }
    };

    f32x4 acc[4][2] = {};
    const int wm = (w & 1) * 64;               // 2 M-groups
    const int wn = (w >> 1) * 32;              // 4 N-groups

    const int nIter = kc >> 5;
    stage(0, k0base);                          // 2 loads in flight
    int cur = 0;
    for (int it = 0; it < nIter; ++it) {
        const int nxt = (cur == 2) ? 0 : cur + 1;
        if (it + 1 < nIter) {
            stage(nxt, k0base + (it + 1) * 32);            // +2 -> 4 in flight
            asm volatile("s_waitcnt vmcnt(2)" ::: "memory"); // drain stage(it)
        } else {
            asm volatile("s_waitcnt vmcnt(0)" ::: "memory");
        }
        __builtin_amdgcn_s_barrier();
        asm volatile("" ::: "memory");

        half8 ah[4], bh[2];
#pragma unroll
        for (int mt = 0; mt < 4; ++mt)
            ah[mt] = *(const half8*)&smA[cur][(((w & 1) * 4 + mt) * 512) + lq * 128 + lr * 8];
#pragma unroll
        for (int nt = 0; nt < 2; ++nt)
            bh[nt] = *(const half8*)&smB[cur][(((w >> 1) * 2 + nt) * 512) + lq * 128 + lr * 8];
#pragma unroll
        for (int mt = 0; mt < 4; ++mt)
#pragma unroll
            for (int nt = 0; nt < 2; ++nt)
                acc[mt][nt] = __builtin_amdgcn_mfma_f32_16x16x32_f16(ah[mt], bh[nt], acc[mt][nt], 0, 0, 0);
        cur = nxt;
    }

    // C/D layout: col = lane&15, row = (lane>>4)*4 + reg  [m89/m91]
#pragma unroll
    for (int mt = 0; mt < 4; ++mt)
#pragma unroll
        for (int nt = 0; nt < 2; ++nt)
#pragma unroll
            for (int r = 0; r < 4; ++r) {
                int row = bm + wm + mt * 16 + lq * 4 + r;
                int col = bn + wn + nt * 16 + lr;
                if (col >= N) continue;
                if (HALF_OUT) Ch[(long)row * ldc + col] = f2h(acc[mt][nt][r]);
                else          Cf[(long)row * ldc + col] = acc[mt][nt][r];
            }
}

// ---------------------------------------------------------------------------
// Depthwise causal conv + bias + SiLU + z-gate SiLU, fused with GEMM1
// split-K merge (p0+p1, fp16 partials). Transposed outputs via padded
// LDS -> coalesced writes. Tile: 64 d x 16 r; grid (64, 24).
// ---------------------------------------------------------------------------
__global__ __launch_bounds__(256) void conv_silu_kernel(
    const ushort_t* __restrict__ p0, const ushort_t* __restrict__ p1,
    const float* __restrict__ conv_w, const float* __restrict__ conv_b,
    float* __restrict__ xconvT, float* __restrict__ zsiluT,
    ushort_t* __restrict__ xc)
{
    __shared__ float Tx[64][17];
    __shared__ float Tz[64][17];
    const int rb = blockIdx.x;             // r tile (16 rows)
    const int db = blockIdx.y;             // d tile (64 ch)
    const int dl = threadIdx.x & 63;
    const int d  = db * 64 + dl;
    const int rr = threadIdx.x >> 6;       // 0..3
    const float w0 = conv_w[d * 4 + 0], w1 = conv_w[d * 4 + 1];
    const float w2 = conv_w[d * 4 + 2], w3 = conv_w[d * 4 + 3];
    const float bb = conv_b[d];
#pragma unroll
    for (int q = 0; q < 4; ++q) {
        const int r = rb * 16 + q * 4 + rr;
        const int l = r & (SEQ - 1);
        float acc = bb;
        if (l >= 3) { long o = (long)(r - 3) * N_XZ + d; acc = fmaf(w0, h2f(p0[o]) + h2f(p1[o]), acc); }
        if (l >= 2) { long o = (long)(r - 2) * N_XZ + d; acc = fmaf(w1, h2f(p0[o]) + h2f(p1[o]), acc); }
        if (l >= 1) { long o = (long)(r - 1) * N_XZ + d; acc = fmaf(w2, h2f(p0[o]) + h2f(p1[o]), acc); }
        { long o = (long)r * N_XZ + d; acc = fmaf(w3, h2f(p0[o]) + h2f(p1[o]), acc); }
        float s = acc / (1.f + expf(-acc));
        xc[(long)r * D_INNER + d] = f2h(s);
        long oz = (long)r * N_XZ + D_INNER + d;
        float zv = h2f(p0[oz]) + h2f(p1[oz]);
        Tx[dl][q * 4 + rr] = s;
        Tz[dl][q * 4 + rr] = zv / (1.f + expf(-zv));
    }
    __syncthreads();
    const int rp = threadIdx.x & 15;
    const int dp = threadIdx.x >> 4;       // 0..15
#pragma unroll
    for (int p = 0; p < 4; ++p) {
        int dd = p * 16 + dp;
        long o = (long)(db * 64 + dd) * M_ROWS + rb * 16 + rp;
        xconvT[o] = Tx[dd][rp];
        zsiluT[o] = Tz[dd][rp];
    }
}

// ---------------------------------------------------------------------------
// GEMM3 epilogue: f = sum of 3 fp32 partials (stride ps) -> xd fp16;
// cols >= 1536 also stored transposed fp32 into BCT.
// ---------------------------------------------------------------------------
__global__ __launch_bounds__(256) void ep_xdbl_kernel(
    const float* __restrict__ P, long ps,
    ushort_t* __restrict__ xd, float* __restrict__ BCT)
{
    long i = ((long)blockIdx.x * 256 + threadIdx.x) * 8;
    if (i >= (long)M_ROWS * N_XDBL) return;
    int row = (int)(i / N_XDBL);
    int col = (int)(i - (long)row * N_XDBL);    // multiple of 8
    float f[8];
#pragma unroll
    for (int j = 0; j < 8; ++j) f[j] = P[i + j] + P[i + j + ps] + P[i + j + 2 * ps];
    pack8(f, xd + i);
    if (col >= D_INNER) {
#pragma unroll
        for (int j = 0; j < 8; ++j)
            BCT[(long)(col + j - D_INNER) * M_ROWS + row] = f[j];
    }
}

// ---------------------------------------------------------------------------
// GEMM6 epilogue: out = sum of 6 fp16 partials (stride ps), fp32 out.
// ---------------------------------------------------------------------------
__global__ __launch_bounds__(256) void ep_merge_kernel(
    const ushort_t* __restrict__ P, long ps, float* __restrict__ out)
{
    long i = ((long)blockIdx.x * 256 + threadIdx.x) * 8;
    if (i >= (long)M_ROWS * D_MODEL) return;
    float o[8] = {};
#pragma unroll
    for (int z = 0; z < 6; ++z) {
        ushort8_t v = *(const ushort8_t*)(P + i + z * ps);
#pragma unroll
        for (int j = 0; j < 8; ++j) o[j] += h2f(v[j]);
    }
    *(float4*)(out + i)     = *(float4*)(o);
    *(float4*)(out + i + 4) = *(float4*)(o + 4);
}

// ---------------------------------------------------------------------------
// Scan — one block per (b,d), 4 waves x 4 states; fused softplus merge of
// the 4 fp16 GEMM4 partials; Kogge-Stone lane scan; fp16 uT out.
// ---------------------------------------------------------------------------
__global__ __launch_bounds__(256) void scan_kernel(
    const ushort_t* __restrict__ P, long ps,    // GEMM4 fp16 partials x4
    const float* __restrict__ b_dt,
    const float* __restrict__ xconvT,
    const float* __restrict__ zsiluT,
    const float* __restrict__ BCT,              // (32, 1024)
    const float* __restrict__ A_log,
    const float* __restrict__ Dp,
    ushort_t* __restrict__ uT)
{
    __shared__ float dlT[512];
    __shared__ float xrT[512];
    __shared__ float red[3 * 512];

    const int bid = blockIdx.x;
    const int b   = bid / D_INNER;
    const int d   = bid % D_INNER;
    const int tid = threadIdx.x;
    const int w   = tid >> 6;
    const int t   = tid & 63;
    const long od = (long)d * M_ROWS + b * SEQ;

    const float bdt = b_dt[d];
#pragma unroll
    for (int q = 0; q < 2; ++q) {
        const int l = tid + q * 256;
        float v = h2f(P[od + l]) + h2f(P[od + l + ps]) + h2f(P[od + l + 2 * ps])
                + h2f(P[od + l + 3 * ps]) + bdt;
        float sp = fmaxf(v, 0.f) + log1pf(expf(-fabsf(v)));   // softplus (fused)
        const int li = (l & 7) * 64 + (l >> 3);               // transposed
        dlT[li] = sp;
        xrT[li] = xconvT[od + l];
    }
    __syncthreads();

    float dl[8], xr[8], dx[8], yac[8];
#pragma unroll
    for (int j = 0; j < 8; ++j) {
        dl[j] = dlT[j * 64 + t];
        xr[j] = xrT[j * 64 + t];
        dx[j] = dl[j] * xr[j];
        yac[j] = 0.f;
    }
    const int l0 = 8 * t;

#pragma unroll
    for (int nn = 0; nn < 4; ++nn) {
        const int n = w * 4 + nn;
        const float Adn = -expf(A_log[d * D_STATE + n]);
        const float4* Bp = (const float4*)(BCT + (long)n * M_ROWS + b * SEQ + l0);
        float4 b0 = Bp[0], b1 = Bp[1];
        float Bv[8] = {b0.x, b0.y, b0.z, b0.w, b1.x, b1.y, b1.z, b1.w};
        float c[8], v[8];
#pragma unroll
        for (int j = 0; j < 8; ++j) {
            c[j] = __expf(dl[j] * Adn);
            v[j] = fabsf(dx[j] * Bv[j]);
        }
        // compose tree: (cR*cL, cR*vL + vR), 7 composes, depth 3
        float c01 = c[1] * c[0], v01 = fmaf(c[1], v[0], v[1]);
        float c23 = c[3] * c[2], v23 = fmaf(c[3], v[2], v[3]);
        float c45 = c[5] * c[4], v45 = fmaf(c[5], v[4], v[5]);
        float c67 = c[7] * c[6], v67 = fmaf(c[7], v[6], v[7]);
        float c03 = c23 * c01,  v03 = fmaf(c23, v01, v23);
        float c47 = c67 * c45,  v47 = fmaf(c67, v45, v67);
        float cA  = c47 * c03,  vA  = fmaf(c47, v03, v47);
        // Kogge-Stone inclusive scan over 64 lanes (6 stages)
#pragma unroll
        for (int h = 1; h <= 32; h <<= 1) {
            float cl = __shfl_up(cA, (unsigned)h);
            float vl = __shfl_up(vA, (unsigned)h);
            if (t >= h) { vA = fmaf(cA, vl, vA); cA = cA * cl; }
        }
        float s = __shfl_up(vA, 1u);
        if (t == 0) s = 0.f;
        const float4* Cp = (const float4*)(BCT + (long)(16 + n) * M_ROWS + b * SEQ + l0);
        float4 c0 = Cp[0], c1 = Cp[1];
        float Cv[8] = {c0.x, c0.y, c0.z, c0.w, c1.x, c1.y, c1.z, c1.w};
#pragma unroll
        for (int j = 0; j < 8; ++j) {
            s = fmaf(c[j], s, v[j]);
            yac[j] = fmaf(s, Cv[j], yac[j]);
        }
    }

    if (w) {
#pragma unroll
        for (int j = 0; j < 8; ++j) red[(w - 1) * 512 + j * 64 + t] = yac[j];
    }
    __syncthreads();
    if (w == 0) {
        const float Dpd = Dp[d];
        ushort8_t uo;
#pragma unroll
        for (int j = 0; j < 8; ++j) {
            float y = yac[j] + red[j * 64 + t] + red[512 + j * 64 + t] + red[1024 + j * 64 + t];
            float uv = fmaf(xr[j], Dpd, y) * zsiluT[od + l0 + j];
            uo[j] = f2h(uv);
        }
        *(ushort8_t*)(uT + od + l0) = uo;
    }
}

// ---------------------------------------------------------------------------
// Transpose (fp16 pass-through): uT (1536,1024) -> u (1024,1536).
// ---------------------------------------------------------------------------
__global__ __launch_bounds__(256) void transpose_split_kernel(
    const ushort_t* __restrict__ uT, ushort_t* __restrict__ u)
{
    __shared__ ushort_t T[64][65];
    const int m0 = blockIdx.x * 64;
    const int d0 = blockIdx.y * 64;
    const int c  = threadIdx.x & 63;
    const int rr = threadIdx.x >> 6;
#pragma unroll
    for (int p = 0; p < 64; p += 4)
        T[p + rr][c] = uT[(long)(d0 + p + rr) * M_ROWS + m0 + c];
    __syncthreads();
#pragma unroll
    for (int p = 0; p < 64; p += 4) {
        int rm = p + rr;
        u[(long)(m0 + rm) * D_INNER + (d0 + c)] = T[c][rm];
    }
}

// ---------------------------------------------------------------------------
extern "C" void kernel_launch(void* const* d_in, const int* in_sizes, int n_in,
                              void* d_out, int out_size, void* d_ws, size_t ws_size,
                              hipStream_t stream)
{
    (void)in_sizes; (void)n_in; (void)out_size; (void)ws_size;

    const float* x      = (const float*)d_in[0];
    const float* W_in   = (const float*)d_in[1];
    const float* conv_w = (const float*)d_in[2];
    const float* conv_b = (const float*)d_in[3];
    const float* W_x    = (const float*)d_in[4];
    const float* W_dt   = (const float*)d_in[5];
    const float* b_dt   = (const float*)d_in[6];
    const float* A_log  = (const float*)d_in[7];
    const float* Dp     = (const float*)d_in[8];
    const float* W_out  = (const float*)d_in[9];
    float* out = (float*)d_out;

    // workspace ~66 MB. P (25.2 MB) generations: G1 fp16 z2 (12.6 MB) ->
    // G3 fp32 z3 (19.3 MB) -> G4 fp16 z4 (12.6 MB, scan fuses merge) ->
    // G6 fp16 z6 (9.4 MB). uT fp16. u_i aliases xc (dead after G3).
    float* ws = (float*)d_ws;
    long off = 0;
    float* P      = ws + off; off += 2L * M_ROWS * N_XZ;          // 6,291,456 fl
    float* xconvT = ws + off; off += (long)D_INNER * M_ROWS;
    float* zsiluT = ws + off; off += (long)D_INNER * M_ROWS;
    float* uTbuf  = ws + off; off += (long)D_INNER * M_ROWS / 2;  // fp16
    float* xsbuf  = ws + off; off += (long)M_ROWS * D_MODEL / 2;  // fp16
    float* w1buf  = ws + off; off += (long)N_XZ * D_MODEL / 2;    // fp16
    float* w2buf  = ws + off; off += (long)N_XDBL * D_INNER / 2;  // fp16
    float* wdtbuf = ws + off; off += (long)D_INNER * D_INNER / 2; // fp16
    float* wobuf  = ws + off; off += (long)D_MODEL * D_INNER / 2; // fp16
    float* xcbuf  = ws + off; off += (long)M_ROWS * D_INNER / 2;  // fp16
    float* xdbuf  = ws + off; off += (long)M_ROWS * N_XDBL / 2;   // fp16
    float* BCT    = ws + off; off += (long)2 * D_STATE * M_ROWS;

    ushort_t* xs    = (ushort_t*)xsbuf;
    ushort_t* w1    = (ushort_t*)w1buf;
    ushort_t* w2    = (ushort_t*)w2buf;
    ushort_t* wdt16 = (ushort_t*)wdtbuf;
    ushort_t* wo16  = (ushort_t*)wobuf;
    ushort_t* xc    = (ushort_t*)xcbuf;          // conv fp16 out (G3 A)
    ushort_t* xd    = (ushort_t*)xdbuf;          // x_dbl fp16 (G4 B)
    ushort_t* u_i   = (ushort_t*)xcbuf;          // u fp16 (G6 A; xc dead)
    ushort_t* uT    = (ushort_t*)uTbuf;          // scan out fp16
    ushort_t* P16   = (ushort_t*)P;              // fp16 partial view of P

    const long psG4 = (long)D_INNER * M_ROWS;    // element strides
    const long psG1 = (long)M_ROWS * N_XZ;
    const long psG6 = (long)M_ROWS * D_MODEL;

    dim3 blk(256);
    dim3 gblk(512);

    // 1) pack all fp32 operands -> fp16 (one kernel)
    pack_kernel<<<dim3(SPACK / 2048), blk, 0, stream>>>(
        x, W_in, W_x, W_dt, W_out, xs, w1, w2, wdt16, wo16);
    // 2) xz = x @ W_in^T  (M=1024,N=3072,K=768), z=2 -> fp16 partials
    gemm_lds<1><<<dim3(N_XZ / 128, M_ROWS / 128, 2), gblk, 0, stream>>>(
        xs, D_MODEL, w1, D_MODEL, P16, psG1, N_XZ, N_XZ, D_MODEL / 2);
    // 3) conv + silu (fuses fp16 GEMM1 merge; transposed-write LDS)
    conv_silu_kernel<<<dim3(M_ROWS / 16, D_INNER / 64), blk, 0, stream>>>(
        P16, P16 + psG1, conv_w, conv_b, xconvT, zsiluT, xc);
    // 4) x_dbl partials = xconv @ W_x^T  (M=1024,N=1568,K=1536), z=3, fp32
    gemm_lds<0><<<dim3((N_XDBL + 127) / 128, M_ROWS / 128, 3), gblk, 0, stream>>>(
        xc, D_INNER, w2, D_INNER, P, (long)M_ROWS * N_XDBL, N_XDBL, N_XDBL, D_INNER / 3);
    // 5) merge 3 fp32 partials -> xd fp16 + BCT
    ep_xdbl_kernel<<<dim3((M_ROWS * N_XDBL) / 2048), blk, 0, stream>>>(
        P, (long)M_ROWS * N_XDBL, xd, BCT);
    // 6) delta_pre partials = W_dt @ x_dbl^T  (M=1536,N=1024,K=1536), z=4, fp16
    gemm_lds<1><<<dim3(M_ROWS / 128, D_INNER / 128, 4), gblk, 0, stream>>>(
        wdt16, D_INNER, xd, N_XDBL, P16, psG4, M_ROWS, M_ROWS, D_INNER / 4);
    // 7) scan (fused softplus merge of 4 fp16 partials) -> uT fp16
    scan_kernel<<<dim3(BATCH * D_INNER), blk, 0, stream>>>(
        P16, psG4, b_dt, xconvT, zsiluT, BCT, A_log, Dp, uT);
    // 8) transpose uT -> u fp16 (pass-through)
    transpose_split_kernel<<<dim3(M_ROWS / 64, D_INNER / 64), blk, 0, stream>>>(
        uT, u_i);
    // 9) out partials = u @ W_out^T  (M=1024,N=768,K=1536), z=6, fp16
    gemm_lds<1><<<dim3(D_MODEL / 128, M_ROWS / 128, 6), gblk, 0, stream>>>(
        u_i, D_INNER, wo16, D_INNER, P16, psG6, D_MODEL, D_MODEL, D_INNER / 6);
    // 10) merge 6 fp16 partials -> out fp32
    ep_merge_kernel<<<dim3((M_ROWS * D_MODEL) / 2048), blk, 0, stream>>>(
        P16, psG6, out);
}